// Round 1
// baseline (543.654 us; speedup 1.0000x reference)
//
#include <hip/hip_runtime.h>

// Problem constants (from reference)
#define COLS    2048
#define CPC     32          // cells per column == 32 bits -> one word per column
#define NCELLS  65536       // COLS * CPC
#define SEGS    16
#define SYN     32
#define THRESH  13

// ---------------------------------------------------------------------------
// Kernel 1: active-cell phase.
// Thread per cell. A 64-lane wave covers exactly 2 columns (32 cells each),
// so __ballot gives col_has_pred and the packed active bitmask directly.
// Writes: out_active[NCELLS], ws_mask[2048] (packed active bits),
//         atomicAdd into ws_cnt[0]=n_active_cols, ws_cnt[1]=n_predicted.
// ---------------------------------------------------------------------------
__global__ __launch_bounds__(256) void tm_active_kernel(
    const float* __restrict__ active_columns,
    const float* __restrict__ prev_predictive,
    float* __restrict__ out_active,
    unsigned int* __restrict__ ws_mask,
    int* __restrict__ ws_cnt)
{
    int n = blockIdx.x * 256 + threadIdx.x;   // cell index, grid is exact
    int c = n >> 5;                            // column
    int j = n & 31;                            // cell within column
    int lane = threadIdx.x & 63;

    bool predbit    = prev_predictive[n] > 0.0f;
    bool col_active = active_columns[c] > 0.0f;   // broadcast within 32 lanes, cached

    unsigned long long pb = __ballot(predbit);
    unsigned int colmask = (lane < 32) ? (unsigned int)pb : (unsigned int)(pb >> 32);
    bool has_pred = (colmask != 0u);

    // new_active = col_active ? (has_pred ? predbit : true) : false
    bool active = col_active && (has_pred ? predbit : true);
    out_active[n] = active ? 1.0f : 0.0f;

    unsigned long long ab = __ballot(active);
    if (lane == 0)  ws_mask[c] = (unsigned int)ab;          // column of lanes 0..31
    if (lane == 32) ws_mask[c] = (unsigned int)(ab >> 32);  // column of lanes 32..63

    // anomaly counters: one representative lane (j==0) per column
    bool rep = (j == 0);
    unsigned long long aa = __ballot(rep && col_active);
    unsigned long long pp = __ballot(rep && col_active && has_pred);
    if (lane == 0) {
        atomicAdd(&ws_cnt[0], __popcll(aa));
        atomicAdd(&ws_cnt[1], __popcll(pp));
    }
}

// ---------------------------------------------------------------------------
// Kernel 2: predictive phase (the 268 MB streaming kernel).
// Thread per (cell, segment): 16 consecutive lanes = one cell's 16 segments.
// Each thread streams its segment's 32 synapses with int4/float4 loads
// (128 B per array per thread -> one cache line each), looks the presynaptic
// active bit up in the LDS-resident 8 KB bitmask, then max-reduces over the
// 16-lane group via shfl_xor.
// ---------------------------------------------------------------------------
__global__ __launch_bounds__(256) void tm_predict_kernel(
    const int*   __restrict__ seg_pre,
    const float* __restrict__ seg_perm,
    const unsigned int* __restrict__ ws_mask,
    const int*   __restrict__ ws_cnt,
    float* __restrict__ out_pred,
    float* __restrict__ out_anomaly)
{
    __shared__ unsigned int mask[COLS];   // 8 KB active bitmask
    int tid = threadIdx.x;
    #pragma unroll
    for (int i = 0; i < COLS / 256; ++i)
        mask[tid + 256 * i] = ws_mask[tid + 256 * i];
    __syncthreads();

    size_t t = (size_t)blockIdx.x * 256 + tid;            // segment slot: cell*16 + seg
    const int4*   pre4  = (const int4*)  (seg_pre  + t * SYN);
    const float4* perm4 = (const float4*)(seg_perm + t * SYN);

    int cnt = 0;
    #pragma unroll
    for (int k = 0; k < SYN / 4; ++k) {
        int4   p = pre4[k];
        float4 q = perm4[k];
        cnt += (q.x >= 0.5f && ((mask[(unsigned)p.x >> 5] >> ((unsigned)p.x & 31u)) & 1u)) ? 1 : 0;
        cnt += (q.y >= 0.5f && ((mask[(unsigned)p.y >> 5] >> ((unsigned)p.y & 31u)) & 1u)) ? 1 : 0;
        cnt += (q.z >= 0.5f && ((mask[(unsigned)p.z >> 5] >> ((unsigned)p.z & 31u)) & 1u)) ? 1 : 0;
        cnt += (q.w >= 0.5f && ((mask[(unsigned)p.w >> 5] >> ((unsigned)p.w & 31u)) & 1u)) ? 1 : 0;
    }

    // max over the 16 segments of this cell (lanes t..t+15 within one wave)
    #pragma unroll
    for (int off = 1; off < SEGS; off <<= 1)
        cnt = max(cnt, __shfl_xor(cnt, off, 64));

    if ((tid & (SEGS - 1)) == 0)
        out_pred[t >> 4] = (cnt >= THRESH) ? 1.0f : 0.0f;

    // anomaly (kernel 1's atomics are visible across the kernel boundary)
    if (blockIdx.x == 0 && tid == 0) {
        int na = ws_cnt[0];
        int np = ws_cnt[1];
        *out_anomaly = 1.0f - (float)np / (float)(na > 1 ? na : 1);
    }
}

// ---------------------------------------------------------------------------
// Inputs (setup_inputs order):
//   d_in[0] active_columns  f32 [2048]
//   d_in[1] prev_active     f32 [65536]   (unused by the reference)
//   d_in[2] prev_predictive f32 [65536]
//   d_in[3] seg_pre         i32 [65536*16*32]
//   d_in[4] seg_perm        f32 [65536*16*32]
// Output: f32 [65536 active | 65536 predictive | 1 anomaly]
// Workspace: ws[0..2047] u32 bitmask, ws[2048..2049] i32 counters
// ---------------------------------------------------------------------------
extern "C" void kernel_launch(void* const* d_in, const int* in_sizes, int n_in,
                              void* d_out, int out_size, void* d_ws, size_t ws_size,
                              hipStream_t stream) {
    const float* active_columns  = (const float*)d_in[0];
    const float* prev_predictive = (const float*)d_in[2];
    const int*   seg_pre         = (const int*)d_in[3];
    const float* seg_perm        = (const float*)d_in[4];
    float* out = (float*)d_out;

    unsigned int* ws_mask = (unsigned int*)d_ws;
    int* ws_cnt = (int*)((char*)d_ws + COLS * sizeof(unsigned int));

    hipMemsetAsync(ws_cnt, 0, 2 * sizeof(int), stream);

    tm_active_kernel<<<NCELLS / 256, 256, 0, stream>>>(
        active_columns, prev_predictive, out, ws_mask, ws_cnt);

    tm_predict_kernel<<<(NCELLS * SEGS) / 256, 256, 0, stream>>>(
        seg_pre, seg_perm, ws_mask, ws_cnt,
        out + NCELLS, out + 2 * NCELLS);
}

// Round 2
// 311.379 us; speedup vs baseline: 1.7460x; 1.7460x over previous
//
#include <hip/hip_runtime.h>

// Problem constants (from reference)
#define COLS    2048
#define CPC     32          // cells per column == 32 bits -> one word per column
#define NCELLS  65536       // COLS * CPC
#define SEGS    16
#define SYN     32
#define THRESH  13

#define CELLS_PER_BLOCK 16  // 4 waves x 4 sequential cells each
#define PREDICT_GRID (NCELLS / CELLS_PER_BLOCK)   // 4096 blocks

// ---------------------------------------------------------------------------
// Kernel 1: active-cell phase (unchanged from R1 — correct and tiny).
// ---------------------------------------------------------------------------
__global__ __launch_bounds__(256) void tm_active_kernel(
    const float* __restrict__ active_columns,
    const float* __restrict__ prev_predictive,
    float* __restrict__ out_active,
    unsigned int* __restrict__ ws_mask,
    int* __restrict__ ws_cnt)
{
    int n = blockIdx.x * 256 + threadIdx.x;   // cell index, grid is exact
    int c = n >> 5;                            // column
    int j = n & 31;                            // cell within column
    int lane = threadIdx.x & 63;

    bool predbit    = prev_predictive[n] > 0.0f;
    bool col_active = active_columns[c] > 0.0f;

    unsigned long long pb = __ballot(predbit);
    unsigned int colmask = (lane < 32) ? (unsigned int)pb : (unsigned int)(pb >> 32);
    bool has_pred = (colmask != 0u);

    bool active = col_active && (has_pred ? predbit : true);
    out_active[n] = active ? 1.0f : 0.0f;

    unsigned long long ab = __ballot(active);
    if (lane == 0)  ws_mask[c] = (unsigned int)ab;
    if (lane == 32) ws_mask[c] = (unsigned int)(ab >> 32);

    bool rep = (j == 0);
    unsigned long long aa = __ballot(rep && col_active);
    unsigned long long pp = __ballot(rep && col_active && has_pred);
    if (lane == 0) {
        atomicAdd(&ws_cnt[0], __popcll(aa));
        atomicAdd(&ws_cnt[1], __popcll(pp));
    }
}

// ---------------------------------------------------------------------------
// Kernel 2: predictive phase. ONE WAVE PER CELL, fully coalesced.
//
// A cell's 16 segs x 32 syn = 512 contiguous i32 = 128 int4 elements.
// Lane i reads int4 elements i and i+64 -> every VMEM instruction of the
// wave covers a contiguous, aligned 1 KB span (vs R1's 128B-strided scatter
// that over-fetched 4.36x). Each int4 element e belongs to segment e/8, so
// lane i holds partials for segment i/8 (iter 0) and 8+i/8 (iter 1):
//   pack both partials into one int, butterfly-ADD over the 8-lane group
//   (xor 1,2,4), unpack+max -> per-group segment max, butterfly-MAX across
//   groups (xor 8,16,32), lane 0 writes the cell's predictive bit.
// Each block stages the 8 KB active bitmask in LDS once and processes 16
// cells (4 waves x 4 iterations) to amortize the staging.
// ---------------------------------------------------------------------------
__global__ __launch_bounds__(256) void tm_predict_kernel(
    const int*   __restrict__ seg_pre,
    const float* __restrict__ seg_perm,
    const unsigned int* __restrict__ ws_mask,
    const int*   __restrict__ ws_cnt,
    float* __restrict__ out_pred,
    float* __restrict__ out_anomaly)
{
    __shared__ unsigned int mask[COLS];   // 8 KB active bitmask
    int tid = threadIdx.x;
    #pragma unroll
    for (int i = 0; i < COLS / 256; ++i)
        mask[tid + 256 * i] = ws_mask[tid + 256 * i];
    __syncthreads();

    int wave = tid >> 6;
    int lane = tid & 63;

    #pragma unroll
    for (int it = 0; it < CELLS_PER_BLOCK / 4; ++it) {
        int cell = blockIdx.x * CELLS_PER_BLOCK + it * 4 + wave;

        const int4*   pre4  = (const int4*)  seg_pre  + (size_t)cell * 128;
        const float4* perm4 = (const float4*)seg_perm + (size_t)cell * 128;

        // Issue all four 16B loads up front (coalesced 1 KB per wave-instr).
        int4   p0 = pre4[lane];
        int4   p1 = pre4[lane + 64];
        float4 q0 = perm4[lane];
        float4 q1 = perm4[lane + 64];

        int c0 = 0, c1 = 0;
        c0 += (q0.x >= 0.5f && ((mask[(unsigned)p0.x >> 5] >> ((unsigned)p0.x & 31u)) & 1u)) ? 1 : 0;
        c0 += (q0.y >= 0.5f && ((mask[(unsigned)p0.y >> 5] >> ((unsigned)p0.y & 31u)) & 1u)) ? 1 : 0;
        c0 += (q0.z >= 0.5f && ((mask[(unsigned)p0.z >> 5] >> ((unsigned)p0.z & 31u)) & 1u)) ? 1 : 0;
        c0 += (q0.w >= 0.5f && ((mask[(unsigned)p0.w >> 5] >> ((unsigned)p0.w & 31u)) & 1u)) ? 1 : 0;
        c1 += (q1.x >= 0.5f && ((mask[(unsigned)p1.x >> 5] >> ((unsigned)p1.x & 31u)) & 1u)) ? 1 : 0;
        c1 += (q1.y >= 0.5f && ((mask[(unsigned)p1.y >> 5] >> ((unsigned)p1.y & 31u)) & 1u)) ? 1 : 0;
        c1 += (q1.z >= 0.5f && ((mask[(unsigned)p1.z >> 5] >> ((unsigned)p1.z & 31u)) & 1u)) ? 1 : 0;
        c1 += (q1.w >= 0.5f && ((mask[(unsigned)p1.w >> 5] >> ((unsigned)p1.w & 31u)) & 1u)) ? 1 : 0;

        // Sum partials within each 8-lane segment group (both segs at once).
        int v = c0 | (c1 << 16);
        v += __shfl_xor(v, 1, 64);
        v += __shfl_xor(v, 2, 64);
        v += __shfl_xor(v, 4, 64);
        int m = max(v & 0xffff, v >> 16);   // max(seg lane/8, seg 8+lane/8)
        // Max across the 8 groups -> cell max on every lane.
        m = max(m, __shfl_xor(m, 8, 64));
        m = max(m, __shfl_xor(m, 16, 64));
        m = max(m, __shfl_xor(m, 32, 64));

        if (lane == 0)
            out_pred[cell] = (m >= THRESH) ? 1.0f : 0.0f;
    }

    // anomaly (kernel 1's atomics are visible across the kernel boundary)
    if (blockIdx.x == 0 && tid == 0) {
        int na = ws_cnt[0];
        int np = ws_cnt[1];
        *out_anomaly = 1.0f - (float)np / (float)(na > 1 ? na : 1);
    }
}

// ---------------------------------------------------------------------------
// Inputs (setup_inputs order):
//   d_in[0] active_columns  f32 [2048]
//   d_in[1] prev_active     f32 [65536]   (unused by the reference)
//   d_in[2] prev_predictive f32 [65536]
//   d_in[3] seg_pre         i32 [65536*16*32]
//   d_in[4] seg_perm        f32 [65536*16*32]
// Output: f32 [65536 active | 65536 predictive | 1 anomaly]
// Workspace: ws[0..2047] u32 bitmask, ws[2048..2049] i32 counters
// ---------------------------------------------------------------------------
extern "C" void kernel_launch(void* const* d_in, const int* in_sizes, int n_in,
                              void* d_out, int out_size, void* d_ws, size_t ws_size,
                              hipStream_t stream) {
    const float* active_columns  = (const float*)d_in[0];
    const float* prev_predictive = (const float*)d_in[2];
    const int*   seg_pre         = (const int*)d_in[3];
    const float* seg_perm        = (const float*)d_in[4];
    float* out = (float*)d_out;

    unsigned int* ws_mask = (unsigned int*)d_ws;
    int* ws_cnt = (int*)((char*)d_ws + COLS * sizeof(unsigned int));

    hipMemsetAsync(ws_cnt, 0, 2 * sizeof(int), stream);

    tm_active_kernel<<<NCELLS / 256, 256, 0, stream>>>(
        active_columns, prev_predictive, out, ws_mask, ws_cnt);

    tm_predict_kernel<<<PREDICT_GRID, 256, 0, stream>>>(
        seg_pre, seg_perm, ws_mask, ws_cnt,
        out + NCELLS, out + 2 * NCELLS);
}